// Round 1
// baseline (175.522 us; speedup 1.0000x reference)
//
#include <hip/hip_runtime.h>
#include <hip/hip_bf16.h>

typedef unsigned short u16;
typedef __bf16 bf16x8 __attribute__((ext_vector_type(8)));
typedef float f32x4 __attribute__((ext_vector_type(4)));

#define T_TOTAL 8192
#define F_DIM   2048
#define E_NUM   8
#define R_RANK  16
#define ER_DIM  128
#define O_DIM   2048

__device__ __forceinline__ u16 f2bf(float f) {
  return __builtin_bit_cast(u16, (__bf16)f);  // RTNE fptrunc
}

// ---------------------------------------------------------------------------
// prep: A_stack [E,r,F] fp32 -> Abf [128][2048] bf16 (straight cast)
//       B_stack [E,O,r] fp32 -> BbfT [O=2048][er=128] bf16 (transpose-cast)
// ---------------------------------------------------------------------------
__global__ __launch_bounds__(256) void prep_kernel(
    const float* __restrict__ A, const float* __restrict__ Bst,
    u16* __restrict__ Abf, u16* __restrict__ BbfT) {
  const int i = blockIdx.x * 256 + threadIdx.x;  // 0 .. 128*2048-1
  Abf[i] = f2bf(A[i]);
  const int o = i >> 7, er = i & 127, e = er >> 4, j = er & 15;
  BbfT[i] = f2bf(Bst[e * (O_DIM * R_RANK) + o * R_RANK + j]);
}

// ---------------------------------------------------------------------------
// gemm1: per 16-token block: z_all[16][128] = bf16-MFMA(x, A^T)
//        + fp32 sim[16][8] (VALU, from the staging registers)
//        + top-2 / softmax / scale  ->  zc[t][er] = w[t,e] * z  (bf16)
// ---------------------------------------------------------------------------
__global__ __launch_bounds__(256) void gemm1_kernel(
    const float* __restrict__ x, const float* __restrict__ protos,
    const float* __restrict__ scales, const u16* __restrict__ Abf,
    u16* __restrict__ zc) {
  __shared__ u16 xs[16 * 136];        // x tile   [16 t][128 k] bf16, pad->136
  __shared__ u16 as_[128 * 136];      // A tile   [128 er][128 k] bf16
  __shared__ float pk[8 * 128];       // proto chunk [8 e][128 k] fp32
  __shared__ float sim_lds[16][8];
  __shared__ float w_lds[16][8];

  const int tid  = threadIdx.x;
  const int t0   = blockIdx.x * 16;
  const int row  = tid >> 4;          // 0..15 token row
  const int seg  = tid & 15;          // 0..15 k-segment
  const int lane = tid & 63;
  const int wave = tid >> 6;          // 0..3 -> er quadrant of 32
  const int g    = lane >> 4;         // 0..3
  const int lm   = lane & 15;

  float sacc[E_NUM];
#pragma unroll
  for (int e = 0; e < E_NUM; ++e) sacc[e] = 0.f;

  const f32x4 z4 = {0.f, 0.f, 0.f, 0.f};
  f32x4 acc[2];
  acc[0] = z4; acc[1] = z4;

  for (int kt = 0; kt < F_DIM / 128; ++kt) {
    const int kb = kt * 128;
    __syncthreads();  // previous tile fully consumed

    // --- x: 8 fp32 per thread, coalesced 128B-per-quarter-wave ---
    f32x4 xv[2];
    const float* xp = x + (size_t)(t0 + row) * F_DIM + kb + seg * 4;
    xv[0] = *reinterpret_cast<const f32x4*>(xp);
    xv[1] = *reinterpret_cast<const f32x4*>(xp + 64);

    // --- proto chunk -> LDS ---
    {
      const int pe = tid >> 5;            // 0..7
      const int pj = (tid & 31) * 4;      // 0..124
      *reinterpret_cast<f32x4*>(&pk[pe * 128 + pj]) =
          *reinterpret_cast<const f32x4*>(protos + (size_t)pe * F_DIM + kb + pj);
    }

    // --- A tile (already bf16) -> LDS ---
#pragma unroll
    for (int it = 0; it < 8; ++it) {
      const int c  = it * 256 + tid;      // 0..2047
      const int er = c >> 4;
      const int ks = (c & 15) * 8;
      *reinterpret_cast<uint4*>(&as_[er * 136 + ks]) =
          *reinterpret_cast<const uint4*>(Abf + (size_t)er * F_DIM + kb + ks);
    }

    // --- x regs -> bf16 -> LDS ---
#pragma unroll
    for (int p = 0; p < 2; ++p) {
      ushort4 h;
      h.x = f2bf(xv[p][0]); h.y = f2bf(xv[p][1]);
      h.z = f2bf(xv[p][2]); h.w = f2bf(xv[p][3]);
      *reinterpret_cast<ushort4*>(&xs[row * 136 + seg * 4 + p * 64]) = h;
    }
    __syncthreads();

    // --- fp32 sim partial dots (uses live xv registers) ---
#pragma unroll
    for (int p = 0; p < 2; ++p) {
#pragma unroll
      for (int e = 0; e < E_NUM; ++e) {
        f32x4 pv = *reinterpret_cast<const f32x4*>(&pk[e * 128 + seg * 4 + p * 64]);
        sacc[e] += xv[p][0] * pv[0] + xv[p][1] * pv[1] +
                   xv[p][2] * pv[2] + xv[p][3] * pv[3];
      }
    }

    // --- MFMA: wave covers er quadrant [wave*32, wave*32+32) ---
#pragma unroll
    for (int kk = 0; kk < 4; ++kk) {
      bf16x8 av = *reinterpret_cast<const bf16x8*>(&xs[lm * 136 + kk * 32 + g * 8]);
#pragma unroll
      for (int n = 0; n < 2; ++n) {
        bf16x8 bv = *reinterpret_cast<const bf16x8*>(
            &as_[(wave * 32 + n * 16 + lm) * 136 + kk * 32 + g * 8]);
        acc[n] = __builtin_amdgcn_mfma_f32_16x16x32_bf16(av, bv, acc[n], 0, 0, 0);
      }
    }
  }

  // --- reduce sim across the 16 seg-threads (low 4 lane bits) ---
#pragma unroll
  for (int s = 1; s < 16; s <<= 1)
#pragma unroll
    for (int e = 0; e < E_NUM; ++e)
      sacc[e] += __shfl_xor(sacc[e], s);
  if (seg < E_NUM) sim_lds[row][seg] = sacc[seg];
  __syncthreads();

  // --- per-token top-2 + softmax + scale -> w_lds[t][e] ---
  if (tid < 16) {
    float sv[E_NUM];
#pragma unroll
    for (int e = 0; e < E_NUM; ++e) sv[e] = fabsf(sim_lds[tid][e]);
    int e0 = 0; float b0 = sv[0];
#pragma unroll
    for (int e = 1; e < E_NUM; ++e) if (sv[e] > b0) { b0 = sv[e]; e0 = e; }
    int e1 = -1; float b1 = -3.0e38f;
#pragma unroll
    for (int e = 0; e < E_NUM; ++e) if (e != e0 && sv[e] > b1) { b1 = sv[e]; e1 = e; }
    const float d  = expf(b1 - b0);       // <= 1, stable
    const float c0 = 1.f / (1.f + d);
    const float c1 = d * c0;
#pragma unroll
    for (int e = 0; e < E_NUM; ++e) w_lds[tid][e] = 0.f;
    w_lds[tid][e0] = c0 * scales[e0];
    w_lds[tid][e1] = c1 * scales[e1];
  }
  __syncthreads();

  // --- epilogue: zc = w * z_all (bf16). C/D layout: col=lm, row=g*4+i ---
#pragma unroll
  for (int n = 0; n < 2; ++n) {
    const int er = wave * 32 + n * 16 + lm;
    const int e  = er >> 4;               // wave-uniform
#pragma unroll
    for (int i = 0; i < 4; ++i) {
      const int tl = g * 4 + i;
      zc[(size_t)(t0 + tl) * ER_DIM + er] = f2bf(acc[n][i] * w_lds[tl][e]);
    }
  }
}

// ---------------------------------------------------------------------------
// gemm2: out[8192][2048] fp32 = zc[8192][128]bf16 @ Bflat[128][2048]bf16
//        (Bflat staged from BbfT [o][er]); K=128 fits in one LDS tile.
// ---------------------------------------------------------------------------
__global__ __launch_bounds__(256) void gemm2_kernel(
    const u16* __restrict__ zc, const u16* __restrict__ BbfT,
    float* __restrict__ out) {
  __shared__ u16 zcs[128 * 136];   // [128 t][128 er]
  __shared__ u16 bbs[64 * 136];    // [64 o][128 er]

  const int tid  = threadIdx.x;
  const int o0   = blockIdx.x * 64;
  const int t0   = blockIdx.y * 128;
  const int lane = tid & 63;
  const int wave = tid >> 6;
  const int wm   = wave >> 1;      // t half (64)
  const int wn   = wave & 1;       // o half (32)
  const int g    = lane >> 4;
  const int lm   = lane & 15;

#pragma unroll
  for (int it = 0; it < 8; ++it) {
    const int c = it * 256 + tid;
    const int r = c >> 4;
    const int ks = (c & 15) * 8;
    *reinterpret_cast<uint4*>(&zcs[r * 136 + ks]) =
        *reinterpret_cast<const uint4*>(zc + (size_t)(t0 + r) * ER_DIM + ks);
  }
#pragma unroll
  for (int it = 0; it < 4; ++it) {
    const int c = it * 256 + tid;
    const int r = c >> 4;
    const int ks = (c & 15) * 8;
    *reinterpret_cast<uint4*>(&bbs[r * 136 + ks]) =
        *reinterpret_cast<const uint4*>(BbfT + (size_t)(o0 + r) * ER_DIM + ks);
  }
  __syncthreads();

  const f32x4 z4 = {0.f, 0.f, 0.f, 0.f};
  f32x4 acc[4][2];
#pragma unroll
  for (int m = 0; m < 4; ++m)
#pragma unroll
    for (int n = 0; n < 2; ++n) acc[m][n] = z4;

#pragma unroll
  for (int kk = 0; kk < 4; ++kk) {
    bf16x8 av[4], bv[2];
#pragma unroll
    for (int m = 0; m < 4; ++m)
      av[m] = *reinterpret_cast<const bf16x8*>(
          &zcs[(wm * 64 + m * 16 + lm) * 136 + kk * 32 + g * 8]);
#pragma unroll
    for (int n = 0; n < 2; ++n)
      bv[n] = *reinterpret_cast<const bf16x8*>(
          &bbs[(wn * 32 + n * 16 + lm) * 136 + kk * 32 + g * 8]);
#pragma unroll
    for (int m = 0; m < 4; ++m)
#pragma unroll
      for (int n = 0; n < 2; ++n)
        acc[m][n] = __builtin_amdgcn_mfma_f32_16x16x32_bf16(av[m], bv[n], acc[m][n], 0, 0, 0);
  }

#pragma unroll
  for (int m = 0; m < 4; ++m) {
#pragma unroll
    for (int n = 0; n < 2; ++n) {
      const int o = o0 + wn * 32 + n * 16 + lm;
#pragma unroll
      for (int i = 0; i < 4; ++i) {
        const int t = t0 + wm * 64 + m * 16 + g * 4 + i;
        out[(size_t)t * O_DIM + o] = acc[m][n][i];
      }
    }
  }
}

// ---------------------------------------------------------------------------
extern "C" void kernel_launch(void* const* d_in, const int* in_sizes, int n_in,
                              void* d_out, int out_size, void* d_ws, size_t ws_size,
                              hipStream_t stream) {
  const float* x      = (const float*)d_in[0];
  const float* protos = (const float*)d_in[1];
  const float* A      = (const float*)d_in[2];
  const float* Bst    = (const float*)d_in[3];
  const float* scales = (const float*)d_in[4];
  // d_in[5] = top_k (always 2 for this problem)

  u16* zcw  = (u16*)d_ws;                              // 8192*128 bf16
  u16* Abf  = zcw + (size_t)T_TOTAL * ER_DIM;          // 128*2048 bf16
  u16* BbfT = Abf + (size_t)ER_DIM * F_DIM;            // 2048*128 bf16
  float* out = (float*)d_out;

  prep_kernel<<<(ER_DIM * F_DIM) / 256, 256, 0, stream>>>(A, Bst, Abf, BbfT);
  gemm1_kernel<<<T_TOTAL / 16, 256, 0, stream>>>(x, protos, scales, Abf, zcw);
  gemm2_kernel<<<dim3(O_DIM / 64, T_TOTAL / 128), 256, 0, stream>>>(zcw, BbfT, out);
}

// Round 3
// 142.657 us; speedup vs baseline: 1.2304x; 1.2304x over previous
//
#include <hip/hip_runtime.h>
#include <hip/hip_bf16.h>

typedef unsigned short u16;
typedef __bf16 bf16x8 __attribute__((ext_vector_type(8)));
typedef float f32x4 __attribute__((ext_vector_type(4)));

#define T_TOTAL 8192
#define F_DIM   2048
#define E_NUM   8
#define ER_DIM  128
#define O_DIM   2048

__device__ __forceinline__ u16 f2bf(float f) {
  return __builtin_bit_cast(u16, (__bf16)f);  // RTNE
}
__device__ __forceinline__ unsigned pack2(float a, float b) {
  return (unsigned)f2bf(a) | ((unsigned)f2bf(b) << 16);
}
// async global->LDS, 16B per lane (dest must be wave-uniform-base + lane*16)
__device__ __forceinline__ void gld16(void* lds, const void* g) {
  __builtin_amdgcn_global_load_lds(
      (const __attribute__((address_space(1))) unsigned int*)g,
      (__attribute__((address_space(3))) unsigned int*)lds, 16, 0, 0);
}

// ---------------------------------------------------------------------------
// prep: A_stack [E,r,F] f32 -> Abf_sw [128][2048] bf16, XOR-swizzled per
//       128-elem K-chunk: Abf_sw[r][c] = A[r][c ^ ((r&7)<<3)]
//       B_stack [E,O,r] f32 -> BbfT_sw [2048 o][128 er] bf16, same swizzle.
// ---------------------------------------------------------------------------
__global__ __launch_bounds__(256) void prep_kernel(
    const float* __restrict__ A, const float* __restrict__ Bst,
    u16* __restrict__ Abf, u16* __restrict__ BbfT) {
  const int i = blockIdx.x * 256 + threadIdx.x;  // 0 .. 128*2048-1
  {
    const int r = i >> 11, c = i & 2047;
    Abf[i] = f2bf(A[r * F_DIM + (c ^ ((r & 7) << 3))]);
  }
  {
    const int o = i >> 7, ep = i & 127;
    const int er = ep ^ ((o & 7) << 3);
    const int e = er >> 4, j = er & 15;
    BbfT[i] = f2bf(Bst[e * (O_DIM * 16) + o * 16 + j]);
  }
}

// ---------------------------------------------------------------------------
// gemm1: 32 tokens/block, 512 threads (8 waves), 256 blocks (1/CU).
// Double-buffered LDS, one barrier per K-step, DMA staging for A & protos,
// x via registers (fp32 sim + bf16 convert), swizzled linear LDS layouts.
// Wave w owns er-slice [w*16, w*16+16)  (== expert w).
// ---------------------------------------------------------------------------
__global__ __launch_bounds__(512, 2) void gemm1_kernel(
    const float* __restrict__ x, const float* __restrict__ protos,
    const float* __restrict__ scales, const u16* __restrict__ Abf,
    u16* __restrict__ zc) {
  __shared__ u16  as_[2][128 * 128];   // 64 KB  A tiles (swizzled content)
  __shared__ u16  xs [2][32 * 128];    // 16 KB  x tiles bf16 (swizzled)
  __shared__ float pk[2][8 * 128];     // 8 KB   proto chunks f32 (linear)
  __shared__ float sim_lds[32][8];
  __shared__ float w_lds[32][8];

  const int tid  = threadIdx.x;
  const int t0   = blockIdx.x * 32;
  const int row  = tid >> 4;          // 0..31 token
  const int seg  = tid & 15;          // 0..15 k-segment (8 floats each)
  const int lane = tid & 63;
  const int w    = tid >> 6;          // 0..7 wave -> er slice / expert
  const int g    = lane >> 4;
  const int lm   = lane & 15;

  float sacc[E_NUM];
#pragma unroll
  for (int e = 0; e < E_NUM; ++e) sacc[e] = 0.f;
  const f32x4 z4 = {0.f, 0.f, 0.f, 0.f};
  f32x4 acc[2];
  acc[0] = z4; acc[1] = z4;

  // ---- prologue: stage tile 0 ----
#pragma unroll
  for (int it = 0; it < 4; ++it) {
    const int c = it * 512 + tid;            // 16B chunk id, 0..2047
    const int r = c >> 4, ks = (c & 15) * 8;
    gld16(&as_[0][c * 8], Abf + (size_t)r * F_DIM + ks);
  }
  if (tid < 256)
    gld16(&pk[0][tid * 4], protos + (size_t)(tid >> 5) * F_DIM + (tid & 31) * 4);

  const float* xrow = x + (size_t)(t0 + row) * F_DIM + seg * 8;
  f32x4 xv0 = *reinterpret_cast<const f32x4*>(xrow);
  f32x4 xv1 = *reinterpret_cast<const f32x4*>(xrow + 4);
  {
    uint4 hv;
    hv.x = pack2(xv0[0], xv0[1]); hv.y = pack2(xv0[2], xv0[3]);
    hv.z = pack2(xv1[0], xv1[1]); hv.w = pack2(xv1[2], xv1[3]);
    *reinterpret_cast<uint4*>(
        &xs[0][row * 128 + ((seg * 8) ^ ((row & 7) << 3))]) = hv;
  }

  int buf = 0;
  for (int kt = 0; kt < F_DIM / 128; ++kt) {
    __syncthreads();   // tile kt fully staged (DMA drained + ds_writes)

    f32x4 xn0, xn1;
    if (kt < 15) {
      const int kb = (kt + 1) * 128;
      // issue next A tile DMA into buf^1
#pragma unroll
      for (int it = 0; it < 4; ++it) {
        const int c = it * 512 + tid;
        const int r = c >> 4, ks = (c & 15) * 8;
        gld16(&as_[buf ^ 1][c * 8], Abf + (size_t)r * F_DIM + kb + ks);
      }
      if (tid < 256)
        gld16(&pk[buf ^ 1][tid * 4],
              protos + (size_t)(tid >> 5) * F_DIM + kb + (tid & 31) * 4);
      // issue next x loads (regs)
      xn0 = *reinterpret_cast<const f32x4*>(xrow + kb);
      xn1 = *reinterpret_cast<const f32x4*>(xrow + kb + 4);
    }

    // ---- fp32 sim partials (current tile, register xv + LDS pk) ----
#pragma unroll
    for (int e = 0; e < E_NUM; ++e) {
      f32x4 p0 = *reinterpret_cast<const f32x4*>(&pk[buf][e * 128 + seg * 8]);
      f32x4 p1 = *reinterpret_cast<const f32x4*>(&pk[buf][e * 128 + seg * 8 + 4]);
      sacc[e] += xv0[0]*p0[0] + xv0[1]*p0[1] + xv0[2]*p0[2] + xv0[3]*p0[3]
               + xv1[0]*p1[0] + xv1[1]*p1[1] + xv1[2]*p1[2] + xv1[3]*p1[3];
    }

    // ---- MFMA: z-slice for er in [w*16, w*16+16) ----
#pragma unroll
    for (int kk = 0; kk < 4; ++kk) {
      const int cb = (kk * 32 + g * 8) ^ ((lm & 7) << 3);
      bf16x8 bv = *reinterpret_cast<const bf16x8*>(
          &as_[buf][(w * 16 + lm) * 128 + cb]);
#pragma unroll
      for (int m = 0; m < 2; ++m) {
        bf16x8 av = *reinterpret_cast<const bf16x8*>(
            &xs[buf][(m * 16 + lm) * 128 + cb]);
        acc[m] = __builtin_amdgcn_mfma_f32_16x16x32_bf16(av, bv, acc[m], 0, 0, 0);
      }
    }

    if (kt < 15) {
      uint4 hv;
      hv.x = pack2(xn0[0], xn0[1]); hv.y = pack2(xn0[2], xn0[3]);
      hv.z = pack2(xn1[0], xn1[1]); hv.w = pack2(xn1[2], xn1[3]);
      *reinterpret_cast<uint4*>(
          &xs[buf ^ 1][row * 128 + ((seg * 8) ^ ((row & 7) << 3))]) = hv;
      xv0 = xn0; xv1 = xn1;
    }
    buf ^= 1;
  }

  // ---- sim reduction over the 16 seg-lanes ----
#pragma unroll
  for (int s = 1; s < 16; s <<= 1)
#pragma unroll
    for (int e = 0; e < E_NUM; ++e) sacc[e] += __shfl_xor(sacc[e], s);
  if (seg < E_NUM) sim_lds[row][seg] = sacc[seg];
  __syncthreads();

  // ---- top-2 + softmax + scale ----
  if (tid < 32) {
    float sv[E_NUM];
#pragma unroll
    for (int e = 0; e < E_NUM; ++e) sv[e] = fabsf(sim_lds[tid][e]);
    int e0 = 0; float b0 = sv[0];
#pragma unroll
    for (int e = 1; e < E_NUM; ++e) if (sv[e] > b0) { b0 = sv[e]; e0 = e; }
    int e1 = -1; float b1 = -3.0e38f;
#pragma unroll
    for (int e = 0; e < E_NUM; ++e) if (e != e0 && sv[e] > b1) { b1 = sv[e]; e1 = e; }
    const float d  = expf(b1 - b0);
    const float c0 = 1.f / (1.f + d);
    const float c1 = d * c0;
#pragma unroll
    for (int e = 0; e < E_NUM; ++e) w_lds[tid][e] = 0.f;
    w_lds[tid][e0] = c0 * scales[e0];
    w_lds[tid][e1] = c1 * scales[e1];
  }
  __syncthreads();

  // ---- epilogue: zc_sw[t][er ^ ((t&7)<<3)] = w[t][w] * z ----
#pragma unroll
  for (int m = 0; m < 2; ++m) {
#pragma unroll
    for (int i = 0; i < 4; ++i) {
      const int tl = m * 16 + g * 4 + i;
      const int er = w * 16 + lm;
      zc[(size_t)(t0 + tl) * ER_DIM + (er ^ ((tl & 7) << 3))] =
          f2bf(acc[m][i] * w_lds[tl][w]);
    }
  }
}

// ---------------------------------------------------------------------------
// gemm2: out[8192][2048] f32 = zc_sw @ BbfT_sw^T ; 128x128 tile, K=128.
// DMA staging (linear, pre-swizzled sources), LDS-repacked f32x4 stores.
// ---------------------------------------------------------------------------
__global__ __launch_bounds__(256, 2) void gemm2_kernel(
    const u16* __restrict__ zc, const u16* __restrict__ BbfT,
    float* __restrict__ out) {
  __shared__ char smem[128 * 132 * 4];             // 67.6 KB
  u16*   zcs = (u16*)smem;                         // [128 t][128 er] 32 KB
  u16*   bbs = zcs + 128 * 128;                    // [128 o][128 er] 32 KB
  float* ob  = (float*)smem;                       // [128][132] reuse

  const int tid  = threadIdx.x;
  const int o0   = blockIdx.x * 128;
  const int t0   = blockIdx.y * 128;
  const int lane = tid & 63;
  const int w    = tid >> 6;
  const int wm   = w >> 1, wn = w & 1;
  const int g    = lane >> 4, lm = lane & 15;

#pragma unroll
  for (int it = 0; it < 8; ++it) {
    const int c = it * 256 + tid;                  // 16B chunk, 0..2047
    gld16(&zcs[c * 8], zc + (size_t)t0 * ER_DIM + c * 8);
  }
#pragma unroll
  for (int it = 0; it < 8; ++it) {
    const int c = it * 256 + tid;
    gld16(&bbs[c * 8], BbfT + (size_t)o0 * ER_DIM + c * 8);
  }
  __syncthreads();

  const f32x4 z4 = {0.f, 0.f, 0.f, 0.f};
  f32x4 acc[4][4];
#pragma unroll
  for (int m = 0; m < 4; ++m)
#pragma unroll
    for (int n = 0; n < 4; ++n) acc[m][n] = z4;

#pragma unroll
  for (int kk = 0; kk < 4; ++kk) {
    const int cb = (kk * 32 + g * 8) ^ ((lm & 7) << 3);
    bf16x8 av[4], bv[4];
#pragma unroll
    for (int m = 0; m < 4; ++m)
      av[m] = *reinterpret_cast<const bf16x8*>(
          &zcs[(wm * 64 + m * 16 + lm) * 128 + cb]);
#pragma unroll
    for (int n = 0; n < 4; ++n)
      bv[n] = *reinterpret_cast<const bf16x8*>(
          &bbs[(wn * 64 + n * 16 + lm) * 128 + cb]);
#pragma unroll
    for (int m = 0; m < 4; ++m)
#pragma unroll
      for (int n = 0; n < 4; ++n)
        acc[m][n] = __builtin_amdgcn_mfma_f32_16x16x32_bf16(av[m], bv[n],
                                                            acc[m][n], 0, 0, 0);
  }
  __syncthreads();   // all frag reads done before smem is reused

  // repack accumulators into ob[128][132]
#pragma unroll
  for (int m = 0; m < 4; ++m)
#pragma unroll
    for (int n = 0; n < 4; ++n)
#pragma unroll
      for (int i = 0; i < 4; ++i)
        ob[(wm * 64 + m * 16 + g * 4 + i) * 132 + wn * 64 + n * 16 + lm] =
            acc[m][n][i];
  __syncthreads();

  // coalesced f32x4 stores
#pragma unroll
  for (int j = 0; j < 16; ++j) {
    const int idx = j * 256 + tid;                 // f32x4 chunk, 0..4095
    const int r = idx >> 5, c = idx & 31;
    f32x4 v = *reinterpret_cast<const f32x4*>(&ob[r * 132 + c * 4]);
    *reinterpret_cast<f32x4*>(&out[(size_t)(t0 + r) * O_DIM + o0 + c * 4]) = v;
  }
}

// ---------------------------------------------------------------------------
extern "C" void kernel_launch(void* const* d_in, const int* in_sizes, int n_in,
                              void* d_out, int out_size, void* d_ws, size_t ws_size,
                              hipStream_t stream) {
  const float* x      = (const float*)d_in[0];
  const float* protos = (const float*)d_in[1];
  const float* A      = (const float*)d_in[2];
  const float* Bst    = (const float*)d_in[3];
  const float* scales = (const float*)d_in[4];
  // d_in[5] = top_k (always 2)

  u16* zcw  = (u16*)d_ws;                              // 8192*128 bf16 (swizzled)
  u16* Abf  = zcw + (size_t)T_TOTAL * ER_DIM;          // 128*2048 bf16 (swizzled)
  u16* BbfT = Abf + (size_t)ER_DIM * F_DIM;            // 2048*128 bf16 (swizzled)
  float* out = (float*)d_out;

  prep_kernel<<<(ER_DIM * F_DIM) / 256, 256, 0, stream>>>(A, Bst, Abf, BbfT);
  gemm1_kernel<<<T_TOTAL / 32, 512, 0, stream>>>(x, protos, scales, Abf, zcw);
  gemm2_kernel<<<dim3(O_DIM / 128, T_TOTAL / 128), 256, 0, stream>>>(zcw, BbfT, out);
}